// Round 7
// baseline (1185.432 us; speedup 1.0000x reference)
//
#include <hip/hip_runtime.h>
#include <stdint.h>

#define HH 1024
#define WW 2048
#define HWN (HH*WW)          // 2097152
#define BIGL HWN             // 'no cluster' sentinel
#define NSLOTS 26
#define MINCL 30
#define THREADS 256
#define MAXCAND 70000        // >= HWN/30 + 1
#define HSZ 512              // per-block LDS label-hash entries
#define TILE 4096            // 64x64 tile
#define NTILES 512           // (1024/64)*(2048/64)
#define SELN 8192            // k_select LDS key cache

// ---------------- global union-find (lock-free, min-root) ----------------
__device__ __forceinline__ int uf_load(int* p, int i) {
    return __hip_atomic_load(&p[i], __ATOMIC_RELAXED, __HIP_MEMORY_SCOPE_AGENT);
}
__device__ __forceinline__ void uf_store(int* p, int i, int v) {
    __hip_atomic_store(&p[i], v, __ATOMIC_RELAXED, __HIP_MEMORY_SCOPE_AGENT);
}
__device__ int uf_find(int* parent, int x) {
    int p = uf_load(parent, x);
    while (p != x) {
        int gp = uf_load(parent, p);
        if (gp != p) uf_store(parent, x, gp);   // path halving (benign race)
        x = p; p = gp;
    }
    return p;
}
__device__ void uf_union(int* parent, int a, int b) {
    int ra = uf_find(parent, a);
    int rb = uf_find(parent, b);
    while (ra != rb) {
        if (ra > rb) { int t = ra; ra = rb; rb = t; }   // hook larger under smaller
        int old = atomicCAS(&parent[rb], rb, ra);
        if (old == rb) return;
        rb = uf_find(parent, old);
        ra = uf_find(parent, ra);
    }
}

// ---------------- LDS union-find (block-local, min-root) ----------------
__device__ __forceinline__ int l_load(int* p, int i) {
    return __hip_atomic_load(&p[i], __ATOMIC_RELAXED, __HIP_MEMORY_SCOPE_WORKGROUP);
}
__device__ __forceinline__ void l_store(int* p, int i, int v) {
    __hip_atomic_store(&p[i], v, __ATOMIC_RELAXED, __HIP_MEMORY_SCOPE_WORKGROUP);
}
__device__ int l_find(int* lp, int x) {
    int p = l_load(lp, x);
    while (p != x) {
        int gp = l_load(lp, p);
        if (gp != p) l_store(lp, x, gp);
        x = p; p = gp;
    }
    return p;
}
__device__ void l_union(int* lp, int a, int b) {
    int ra = l_find(lp, a);
    int rb = l_find(lp, b);
    while (ra != rb) {
        if (ra > rb) { int t = ra; ra = rb; rb = t; }
        int old = atomicCAS(&lp[rb], rb, ra);
        if (old == rb) return;
        rb = l_find(lp, old);
        ra = l_find(lp, ra);
    }
}

// ---------------- fused init + per-tile CC (R5-identical) ----------------
__global__ __launch_bounds__(THREADS) void k_local(const float* __restrict__ mask,
                                                   uint8_t* __restrict__ flags,
                                                   int* __restrict__ parent) {
    __shared__ uint8_t lact[66 * 72];   // halo active map, row stride 72
    __shared__ uint8_t lc8[TILE];
    __shared__ int lp[TILE];
    int tile_x = blockIdx.x & 31, tile_y = blockIdx.x >> 5;
    int r0 = tile_y << 6, c0 = tile_x << 6;
    int tx = threadIdx.x & 15, ty = threadIdx.x >> 4;
    for (int yy = ty; yy < 66; yy += 16) {
        int gr = r0 - 1 + yy;
        for (int xx = tx; xx < 66; xx += 16) {
            int gc = c0 - 1 + xx;
            bool a = false;
            if ((unsigned)gr < HH && (unsigned)gc < WW)
                a = mask[gr * WW + gc] > 0.1f;
            lact[yy * 72 + xx] = a ? 1 : 0;
        }
    }
    __syncthreads();
    for (int li = threadIdx.x; li < TILE; li += THREADS) {
        int lr = li >> 6, lc = li & 63;
        int b = (lr + 1) * 72 + (lc + 1);
        int a = lact[b];
        int cnt = lact[b - 73] + lact[b - 72] + lact[b - 71]
                + lact[b - 1]  + a           + lact[b + 1]
                + lact[b + 71] + lact[b + 72] + lact[b + 73];
        lc8[li] = (uint8_t)(a | ((a && cnt >= 4) ? 2 : 0));  // MIN_SAMPLES=4 incl self
        lp[li] = li;
    }
    __syncthreads();
    {   // flags -> global, 16B per thread
        int row = threadIdx.x >> 2, chunk = threadIdx.x & 3;
        ((uint4*)(flags + (size_t)(r0 + row) * WW + c0))[chunk] =
            ((const uint4*)lc8)[row * 4 + chunk];
    }
    for (int li = threadIdx.x; li < TILE; li += THREADS) {
        if (!(lc8[li] & 2)) continue;
        int lr = li >> 6, lc = li & 63;
        if (lc > 0 && (lc8[li - 1] & 2)) l_union(lp, li, li - 1);
        if (lr > 0) {
            if (lc > 0  && (lc8[li - 65] & 2)) l_union(lp, li, li - 65);
            if (           (lc8[li - 64] & 2)) l_union(lp, li, li - 64);
            if (lc < 63 && (lc8[li - 63] & 2)) l_union(lp, li, li - 63);
        }
    }
    __syncthreads();
    for (int li = threadIdx.x; li < TILE; li += THREADS) {
        if (!(lc8[li] & 2)) continue;
        int root = li, p;
        while ((p = lp[root]) != root) root = p;   // lp stable after barrier
        int gi = (r0 + (li >> 6)) * WW + c0 + (li & 63);
        int gr = (r0 + (root >> 6)) * WW + c0 + (root & 63);
        parent[gi] = gr;
    }
}

// union only tile-crossing edges (R5-identical)
__global__ __launch_bounds__(THREADS) void k_merge(const uint8_t* __restrict__ flags,
                                                   int* __restrict__ parent) {
    int tile_x = blockIdx.x & 31, tile_y = blockIdx.x >> 5;
    int r0 = tile_y << 6, c0 = tile_x << 6;
    int t = threadIdx.x;
    int lane = t & 63;

    if (t < 64) {                                    // top row, lr=0, lc=t
        int r = r0, c = c0 + t, i = r * WW + c;
        bool selfC = (flags[i] & 2) != 0;
        bool nC = false, nwC = false, neC = false;
        if (selfC && r > 0) {
            nC  = (flags[i - WW] & 2) != 0;
            nwC = (c > 0)      && (flags[i - WW - 1] & 2);
            neC = (c < WW - 1) && (flags[i - WW + 1] & 2);
        }
        int did = 0, ra = -1, rb = -1;
        if (selfC && r > 0 && nC) { ra = uf_find(parent, i); rb = uf_find(parent, i - WW); did = 1; }
        int pra = __shfl_up(ra, 1), prb = __shfl_up(rb, 1), pdid = __shfl_up(did, 1);
        bool head = (lane == 0) || !pdid || pra != ra || prb != rb;
        if (did && head) uf_union(parent, ra, rb);
        if (selfC && r > 0) {
            if (t == 0) {
                if (nwC) uf_union(parent, i, i - WW - 1);          // diag tile
                if (!nC && neC) uf_union(parent, i, i - WW + 1);
            } else if (t == 63) {
                if (!nC && nwC) uf_union(parent, i, i - WW - 1);
                if (neC) {
                    bool eC = (c < WW - 1) && (flags[i + 1] & 2);
                    if (!eC) uf_union(parent, i, i - WW + 1);
                    // else: us~E (right tile corner W-edge) and E~NE (its N-edge)
                }
            } else if (!nC) {
                if (nwC) uf_union(parent, i, i - WW - 1);
                if (neC) uf_union(parent, i, i - WW + 1);
            }
        }
        if (t == 0 && selfC && c > 0 && (flags[i - 1] & 2))        // corner W edge
            uf_union(parent, i, i - 1);
    } else if (t < 127) {                            // left col, lr=1..63, lc=0
        int lr = t - 63;
        int r = r0 + lr, c = c0, i = r * WW + c;
        bool selfC = (flags[i] & 2) != 0;
        bool wC = false, nwC = false;
        if (selfC && c > 0) {
            wC  = (flags[i - 1] & 2) != 0;
            nwC = (flags[i - WW - 1] & 2) != 0;      // r >= 1 guaranteed (lr>=1)
        }
        int did = 0, ra = -1, rb = -1;
        if (selfC && wC) { ra = uf_find(parent, i); rb = uf_find(parent, i - 1); did = 1; }
        int pra = __shfl_up(ra, 1), prb = __shfl_up(rb, 1), pdid = __shfl_up(did, 1);
        bool head = (lane == 0) || !pdid || pra != ra || prb != rb;
        if (did && head) uf_union(parent, ra, rb);
        if (selfC && !wC && nwC) uf_union(parent, i, i - WW - 1);  // if wC: NW~W local in left tile
    } else if (t < 190) {                            // right col, lr=1..63, lc=63
        int lr = t - 126;
        int r = r0 + lr, c = c0 + 63, i = r * WW + c;
        bool selfC = (flags[i] & 2) != 0;
        if (selfC && c < WW - 1) {
            bool neC = (flags[i - WW + 1] & 2) != 0;
            bool eC  = (flags[i + 1] & 2) != 0;
            if (neC && !eC) uf_union(parent, i, i - WW + 1);
            // if eC: us~E (right tile W-edge) and E~NE (right tile local N-edge)
        }
    }
}

// border assignment + per-label stats via on-the-fly uf_find (R5-identical),
// plus MINCL-crossing candidate detection in the flush (R6-proven).
__global__ __launch_bounds__(THREADS) void k_border_stats(
        const uint8_t* __restrict__ flags, int* __restrict__ parent,
        int* __restrict__ labfull, int* __restrict__ sizes,
        unsigned long long* __restrict__ colsum,
        int* __restrict__ cand, int* __restrict__ counter) {
    __shared__ int h_lab[HSZ];
    __shared__ int h_sz[HSZ];
    __shared__ unsigned long long h_cs[HSZ];
    for (int t = threadIdx.x; t < HSZ; t += THREADS) {
        h_lab[t] = -1; h_sz[t] = 0; h_cs[t] = 0;
    }
    __syncthreads();

    int i = blockIdx.x * THREADS + threadIdx.x;
    int f = flags[i];
    int lab = BIGL;
    if (f & 2) {
        lab = uf_find(parent, i);
    } else if (f & 1) {              // active non-core: min core-neighbor root in 3x3
        int r = i >> 11, c = i & (WW - 1);
        int m = BIGL;
        #pragma unroll
        for (int dr = -1; dr <= 1; ++dr) {
            int rr = r + dr;
            if (rr < 0 || rr >= HH) continue;
            #pragma unroll
            for (int dc = -1; dc <= 1; ++dc) {
                int cc = c + dc;
                if (cc < 0 || cc >= WW) continue;
                int n = rr * WW + cc;
                if (flags[n] & 2) {
                    int v = uf_find(parent, n);
                    if (v < m) m = v;
                }
            }
        }
        lab = m;                     // BIGL if no core neighbor
    }
    labfull[i] = lab;

    // wave-level run aggregation (WW % 64 == 0: wave never crosses a row)
    int lane = threadIdx.x & 63;
    int labp = __shfl_up(lab, 1);
    bool head = (lane == 0) || (labp != lab);
    unsigned long long hm = __ballot(head);
    if (head && lab < BIGL) {
        unsigned long long rest = (hm >> lane) >> 1;
        int len = rest ? __ffsll((unsigned long long)rest) : (64 - lane);
        long long c0 = (long long)(i & (WW - 1));
        unsigned long long csum =
            (unsigned long long)(c0 * len + (long long)len * (len - 1) / 2);
        unsigned slot = (((unsigned)lab * 2654435761u) >> 20) & (HSZ - 1);
        for (;;) {
            int old = atomicCAS(&h_lab[slot], -1, lab);
            if (old == -1 || old == lab) {
                atomicAdd(&h_sz[slot], len);
                atomicAdd(&h_cs[slot], csum);
                break;
            }
            slot = (slot + 1) & (HSZ - 1);
        }
    }
    __syncthreads();
    for (int t = threadIdx.x; t < HSZ; t += THREADS) {
        int lb = h_lab[t];
        if (lb >= 0) {
            int add = h_sz[t];
            int old = atomicAdd(&sizes[lb], add);
            if (old < MINCL && old + add >= MINCL) {   // exactly one block sees this
                int p = atomicAdd(counter, 1);
                cand[p] = lb;
            }
            atomicAdd(&colsum[lb], h_cs[t]);
        }
    }
}

// rank-based selection: one block, keys computed once into LDS, rank by
// counting smaller keys (LDS broadcast reads). No serial extraction rounds.
__global__ __launch_bounds__(THREADS) void k_select(const int* __restrict__ cand,
                                                    const int* __restrict__ counter,
                                                    const int* __restrict__ sizes,
                                                    const unsigned long long* __restrict__ colsum,
                                                    signed char* __restrict__ chan) {
    __shared__ unsigned long long keys[SELN];
    const int tid = threadIdx.x;
    const int n = *counter;
    const int nl = n < SELN ? n : SELN;
    for (int j = tid; j < nl; j += THREADS) {
        int lab = cand[j];
        float mean = (float)colsum[lab] / (float)sizes[lab];
        keys[j] = ((unsigned long long)__float_as_uint(mean) << 32) | (unsigned int)lab;
    }
    __syncthreads();
    for (int i = tid; i < n; i += THREADS) {
        unsigned long long ki;
        if (i < SELN) ki = keys[i];
        else {
            int lab = cand[i];
            float mean = (float)colsum[lab] / (float)sizes[lab];
            ki = ((unsigned long long)__float_as_uint(mean) << 32) | (unsigned int)lab;
        }
        int rank = 0;
        for (int j = 0; j < nl && rank < NSLOTS; ++j) rank += (keys[j] < ki) ? 1 : 0;
        for (int j = SELN; j < n && rank < NSLOTS; ++j) {     // overflow slow path
            int lab = cand[j];
            float mean = (float)colsum[lab] / (float)sizes[lab];
            unsigned long long kj =
                ((unsigned long long)__float_as_uint(mean) << 32) | (unsigned int)lab;
            rank += (kj < ki) ? 1 : 0;
        }
        if (rank < NSLOTS) chan[(unsigned int)(ki & 0xFFFFFFFFull)] = (signed char)rank;
    }
}

// one-hot 26xHxW int32 output, int4 stores
__global__ __launch_bounds__(THREADS) void k_output(const int* __restrict__ labfull,
                                                    const signed char* __restrict__ chan,
                                                    int* __restrict__ out) {
    int i4 = (blockIdx.x * THREADS + threadIdx.x) * 4;
    int chv[4];
    #pragma unroll
    for (int t = 0; t < 4; ++t) {
        int lab = labfull[i4 + t];
        chv[t] = (lab < BIGL) ? (int)chan[lab] : -1;
    }
    #pragma unroll
    for (int c = 0; c < NSLOTS; ++c) {
        int4 v;
        v.x = (chv[0] == c) ? 1 : 0;
        v.y = (chv[1] == c) ? 1 : 0;
        v.z = (chv[2] == c) ? 1 : 0;
        v.w = (chv[3] == c) ? 1 : 0;
        *(int4*)(out + (size_t)c * HWN + i4) = v;
    }
}

extern "C" void kernel_launch(void* const* d_in, const int* in_sizes, int n_in,
                              void* d_out, int out_size, void* d_ws, size_t ws_size,
                              hipStream_t stream) {
    const float* mask = (const float*)d_in[0];
    int* out = (int*)d_out;

    char* w = (char*)d_ws;
    int* parent                 = (int*)(w);                          //  8 MB
    int* labfull                = (int*)(w + (size_t)HWN * 4);        //  8 MB
    int* sizes                  = (int*)(w + (size_t)HWN * 8);        //  8 MB
    unsigned long long* colsum  = (unsigned long long*)(w + (size_t)HWN * 12); // 16 MB
    uint8_t* flags              = (uint8_t*)(w + (size_t)HWN * 20);   //  2 MB
    signed char* chan           = (signed char*)(w + (size_t)HWN * 21); // 2 MB
    int* cand                   = (int*)(w + (size_t)HWN * 22);       // 280 KB
    int* counter                = (int*)(w + (size_t)HWN * 22 + MAXCAND * 4);

    // ws is re-poisoned 0xAA before every call — re-init what we accumulate into
    hipMemsetAsync(sizes, 0, (size_t)HWN * 4, stream);
    hipMemsetAsync(colsum, 0, (size_t)HWN * 8, stream);
    hipMemsetAsync(chan, 0xFF, (size_t)HWN, stream);    // -1 = no channel
    hipMemsetAsync(counter, 0, 4, stream);

    const int blocks = HWN / THREADS;   // 8192
    k_local       <<<NTILES, THREADS, 0, stream>>>(mask, flags, parent);
    k_merge       <<<NTILES, THREADS, 0, stream>>>(flags, parent);
    k_border_stats<<<blocks, THREADS, 0, stream>>>(flags, parent, labfull, sizes, colsum,
                                                   cand, counter);
    k_select      <<<1, THREADS, 0, stream>>>(cand, counter, sizes, colsum, chan);
    k_output      <<<HWN / (4 * THREADS), THREADS, 0, stream>>>(labfull, chan, out);
}

// Round 8
// 436.493 us; speedup vs baseline: 2.7158x; 2.7158x over previous
//
#include <hip/hip_runtime.h>
#include <stdint.h>

#define HH 1024
#define WW 2048
#define HWN (HH*WW)          // 2097152
#define BIGL HWN             // 'no cluster' sentinel
#define NSLOTS 26
#define MINCL 30
#define THREADS 256
#define MAXCAND 70000        // >= HWN/30 + 1 (2M/30 = 69906 max possible)
#define HSZ 512              // per-block LDS label-hash entries
#define TILE 4096            // 64x64 tile
#define NTILES 512           // (1024/64)*(2048/64)
#define NB 128               // phase-A selection blocks; NB*1024 >= MAXCAND

// ---------------- global union-find (lock-free, min-root) ----------------
__device__ __forceinline__ int uf_load(int* p, int i) {
    return __hip_atomic_load(&p[i], __ATOMIC_RELAXED, __HIP_MEMORY_SCOPE_AGENT);
}
__device__ __forceinline__ void uf_store(int* p, int i, int v) {
    __hip_atomic_store(&p[i], v, __ATOMIC_RELAXED, __HIP_MEMORY_SCOPE_AGENT);
}
__device__ int uf_find(int* parent, int x) {
    int p = uf_load(parent, x);
    while (p != x) {
        int gp = uf_load(parent, p);
        if (gp != p) uf_store(parent, x, gp);   // path halving (benign race)
        x = p; p = gp;
    }
    return p;
}
__device__ void uf_union(int* parent, int a, int b) {
    int ra = uf_find(parent, a);
    int rb = uf_find(parent, b);
    while (ra != rb) {
        if (ra > rb) { int t = ra; ra = rb; rb = t; }   // hook larger under smaller
        int old = atomicCAS(&parent[rb], rb, ra);
        if (old == rb) return;
        rb = uf_find(parent, old);
        ra = uf_find(parent, ra);
    }
}

// ---------------- LDS union-find (block-local, min-root) ----------------
__device__ __forceinline__ int l_load(int* p, int i) {
    return __hip_atomic_load(&p[i], __ATOMIC_RELAXED, __HIP_MEMORY_SCOPE_WORKGROUP);
}
__device__ __forceinline__ void l_store(int* p, int i, int v) {
    __hip_atomic_store(&p[i], v, __ATOMIC_RELAXED, __HIP_MEMORY_SCOPE_WORKGROUP);
}
__device__ int l_find(int* lp, int x) {
    int p = l_load(lp, x);
    while (p != x) {
        int gp = l_load(lp, p);
        if (gp != p) l_store(lp, x, gp);
        x = p; p = gp;
    }
    return p;
}
__device__ void l_union(int* lp, int a, int b) {
    int ra = l_find(lp, a);
    int rb = l_find(lp, b);
    while (ra != rb) {
        if (ra > rb) { int t = ra; ra = rb; rb = t; }
        int old = atomicCAS(&lp[rb], rb, ra);
        if (old == rb) return;
        rb = l_find(lp, old);
        ra = l_find(lp, ra);
    }
}

// ---------------- fused init + per-tile CC (R5-identical) ----------------
__global__ __launch_bounds__(THREADS) void k_local(const float* __restrict__ mask,
                                                   uint8_t* __restrict__ flags,
                                                   int* __restrict__ parent) {
    __shared__ uint8_t lact[66 * 72];   // halo active map, row stride 72
    __shared__ uint8_t lc8[TILE];
    __shared__ int lp[TILE];
    int tile_x = blockIdx.x & 31, tile_y = blockIdx.x >> 5;
    int r0 = tile_y << 6, c0 = tile_x << 6;
    int tx = threadIdx.x & 15, ty = threadIdx.x >> 4;
    for (int yy = ty; yy < 66; yy += 16) {
        int gr = r0 - 1 + yy;
        for (int xx = tx; xx < 66; xx += 16) {
            int gc = c0 - 1 + xx;
            bool a = false;
            if ((unsigned)gr < HH && (unsigned)gc < WW)
                a = mask[gr * WW + gc] > 0.1f;
            lact[yy * 72 + xx] = a ? 1 : 0;
        }
    }
    __syncthreads();
    for (int li = threadIdx.x; li < TILE; li += THREADS) {
        int lr = li >> 6, lc = li & 63;
        int b = (lr + 1) * 72 + (lc + 1);
        int a = lact[b];
        int cnt = lact[b - 73] + lact[b - 72] + lact[b - 71]
                + lact[b - 1]  + a           + lact[b + 1]
                + lact[b + 71] + lact[b + 72] + lact[b + 73];
        lc8[li] = (uint8_t)(a | ((a && cnt >= 4) ? 2 : 0));  // MIN_SAMPLES=4 incl self
        lp[li] = li;
    }
    __syncthreads();
    {   // flags -> global, 16B per thread
        int row = threadIdx.x >> 2, chunk = threadIdx.x & 3;
        ((uint4*)(flags + (size_t)(r0 + row) * WW + c0))[chunk] =
            ((const uint4*)lc8)[row * 4 + chunk];
    }
    for (int li = threadIdx.x; li < TILE; li += THREADS) {
        if (!(lc8[li] & 2)) continue;
        int lr = li >> 6, lc = li & 63;
        if (lc > 0 && (lc8[li - 1] & 2)) l_union(lp, li, li - 1);
        if (lr > 0) {
            if (lc > 0  && (lc8[li - 65] & 2)) l_union(lp, li, li - 65);
            if (           (lc8[li - 64] & 2)) l_union(lp, li, li - 64);
            if (lc < 63 && (lc8[li - 63] & 2)) l_union(lp, li, li - 63);
        }
    }
    __syncthreads();
    for (int li = threadIdx.x; li < TILE; li += THREADS) {
        if (!(lc8[li] & 2)) continue;
        int root = li, p;
        while ((p = lp[root]) != root) root = p;   // lp stable after barrier
        int gi = (r0 + (li >> 6)) * WW + c0 + (li & 63);
        int gr = (r0 + (root >> 6)) * WW + c0 + (root & 63);
        parent[gi] = gr;
    }
}

// union only tile-crossing edges (R5-identical)
__global__ __launch_bounds__(THREADS) void k_merge(const uint8_t* __restrict__ flags,
                                                   int* __restrict__ parent) {
    int tile_x = blockIdx.x & 31, tile_y = blockIdx.x >> 5;
    int r0 = tile_y << 6, c0 = tile_x << 6;
    int t = threadIdx.x;
    int lane = t & 63;

    if (t < 64) {                                    // top row, lr=0, lc=t
        int r = r0, c = c0 + t, i = r * WW + c;
        bool selfC = (flags[i] & 2) != 0;
        bool nC = false, nwC = false, neC = false;
        if (selfC && r > 0) {
            nC  = (flags[i - WW] & 2) != 0;
            nwC = (c > 0)      && (flags[i - WW - 1] & 2);
            neC = (c < WW - 1) && (flags[i - WW + 1] & 2);
        }
        int did = 0, ra = -1, rb = -1;
        if (selfC && r > 0 && nC) { ra = uf_find(parent, i); rb = uf_find(parent, i - WW); did = 1; }
        int pra = __shfl_up(ra, 1), prb = __shfl_up(rb, 1), pdid = __shfl_up(did, 1);
        bool head = (lane == 0) || !pdid || pra != ra || prb != rb;
        if (did && head) uf_union(parent, ra, rb);
        if (selfC && r > 0) {
            if (t == 0) {
                if (nwC) uf_union(parent, i, i - WW - 1);          // diag tile
                if (!nC && neC) uf_union(parent, i, i - WW + 1);
            } else if (t == 63) {
                if (!nC && nwC) uf_union(parent, i, i - WW - 1);
                if (neC) {
                    bool eC = (c < WW - 1) && (flags[i + 1] & 2);
                    if (!eC) uf_union(parent, i, i - WW + 1);
                    // else: us~E (right tile corner W-edge) and E~NE (its N-edge)
                }
            } else if (!nC) {
                if (nwC) uf_union(parent, i, i - WW - 1);
                if (neC) uf_union(parent, i, i - WW + 1);
            }
        }
        if (t == 0 && selfC && c > 0 && (flags[i - 1] & 2))        // corner W edge
            uf_union(parent, i, i - 1);
    } else if (t < 127) {                            // left col, lr=1..63, lc=0
        int lr = t - 63;
        int r = r0 + lr, c = c0, i = r * WW + c;
        bool selfC = (flags[i] & 2) != 0;
        bool wC = false, nwC = false;
        if (selfC && c > 0) {
            wC  = (flags[i - 1] & 2) != 0;
            nwC = (flags[i - WW - 1] & 2) != 0;      // r >= 1 guaranteed (lr>=1)
        }
        int did = 0, ra = -1, rb = -1;
        if (selfC && wC) { ra = uf_find(parent, i); rb = uf_find(parent, i - 1); did = 1; }
        int pra = __shfl_up(ra, 1), prb = __shfl_up(rb, 1), pdid = __shfl_up(did, 1);
        bool head = (lane == 0) || !pdid || pra != ra || prb != rb;
        if (did && head) uf_union(parent, ra, rb);
        if (selfC && !wC && nwC) uf_union(parent, i, i - WW - 1);  // if wC: NW~W local in left tile
    } else if (t < 190) {                            // right col, lr=1..63, lc=63
        int lr = t - 126;
        int r = r0 + lr, c = c0 + 63, i = r * WW + c;
        bool selfC = (flags[i] & 2) != 0;
        if (selfC && c < WW - 1) {
            bool neC = (flags[i - WW + 1] & 2) != 0;
            bool eC  = (flags[i + 1] & 2) != 0;
            if (neC && !eC) uf_union(parent, i, i - WW + 1);
            // if eC: us~E (right tile W-edge) and E~NE (right tile local N-edge)
        }
    }
}

// border assignment + per-label stats via on-the-fly uf_find (R7-identical)
__global__ __launch_bounds__(THREADS) void k_border_stats(
        const uint8_t* __restrict__ flags, int* __restrict__ parent,
        int* __restrict__ labfull, int* __restrict__ sizes,
        unsigned long long* __restrict__ colsum,
        int* __restrict__ cand, int* __restrict__ counter) {
    __shared__ int h_lab[HSZ];
    __shared__ int h_sz[HSZ];
    __shared__ unsigned long long h_cs[HSZ];
    for (int t = threadIdx.x; t < HSZ; t += THREADS) {
        h_lab[t] = -1; h_sz[t] = 0; h_cs[t] = 0;
    }
    __syncthreads();

    int i = blockIdx.x * THREADS + threadIdx.x;
    int f = flags[i];
    int lab = BIGL;
    if (f & 2) {
        lab = uf_find(parent, i);
    } else if (f & 1) {              // active non-core: min core-neighbor root in 3x3
        int r = i >> 11, c = i & (WW - 1);
        int m = BIGL;
        #pragma unroll
        for (int dr = -1; dr <= 1; ++dr) {
            int rr = r + dr;
            if (rr < 0 || rr >= HH) continue;
            #pragma unroll
            for (int dc = -1; dc <= 1; ++dc) {
                int cc = c + dc;
                if (cc < 0 || cc >= WW) continue;
                int n = rr * WW + cc;
                if (flags[n] & 2) {
                    int v = uf_find(parent, n);
                    if (v < m) m = v;
                }
            }
        }
        lab = m;                     // BIGL if no core neighbor
    }
    labfull[i] = lab;

    // wave-level run aggregation (WW % 64 == 0: wave never crosses a row)
    int lane = threadIdx.x & 63;
    int labp = __shfl_up(lab, 1);
    bool head = (lane == 0) || (labp != lab);
    unsigned long long hm = __ballot(head);
    if (head && lab < BIGL) {
        unsigned long long rest = (hm >> lane) >> 1;
        int len = rest ? __ffsll((unsigned long long)rest) : (64 - lane);
        long long c0 = (long long)(i & (WW - 1));
        unsigned long long csum =
            (unsigned long long)(c0 * len + (long long)len * (len - 1) / 2);
        unsigned slot = (((unsigned)lab * 2654435761u) >> 20) & (HSZ - 1);
        for (;;) {
            int old = atomicCAS(&h_lab[slot], -1, lab);
            if (old == -1 || old == lab) {
                atomicAdd(&h_sz[slot], len);
                atomicAdd(&h_cs[slot], csum);
                break;
            }
            slot = (slot + 1) & (HSZ - 1);
        }
    }
    __syncthreads();
    for (int t = threadIdx.x; t < HSZ; t += THREADS) {
        int lb = h_lab[t];
        if (lb >= 0) {
            int add = h_sz[t];
            int old = atomicAdd(&sizes[lb], add);
            if (old < MINCL && old + add >= MINCL) {   // exactly one block sees this
                int p = atomicAdd(counter, 1);
                cand[p] = lb;
            }
            atomicAdd(&colsum[lb], h_cs[t]);
        }
    }
}

// ---- two-phase parallel top-26 selection (n can be ~50k) ----
// Phase A: NB blocks, each extracts its slice's local top-26 into top26g.
__global__ __launch_bounds__(THREADS) void k_sel1(const int* __restrict__ cand,
                                                  const int* __restrict__ counter,
                                                  const int* __restrict__ sizes,
                                                  const unsigned long long* __restrict__ colsum,
                                                  unsigned long long* __restrict__ top26g) {
    __shared__ unsigned long long keys[1024];     // slice <= ceil(70000/128) = 547
    __shared__ unsigned long long skey[THREADS];
    __shared__ int sidx[THREADS];
    const int tid = threadIdx.x;
    int n = *counter;
    int slice = (n + NB - 1) / NB;
    if (slice > 1024) slice = 1024;               // unreachable (n <= MAXCAND)
    int j0 = blockIdx.x * slice;
    int j1 = j0 + slice; if (j1 > n) j1 = n;
    int len = j1 - j0; if (len < 0) len = 0;
    for (int t = tid; t < len; t += THREADS) {
        int lab = cand[j0 + t];
        float mean = (float)colsum[lab] / (float)sizes[lab];
        keys[t] = ((unsigned long long)__float_as_uint(mean) << 32) | (unsigned int)lab;
    }
    __syncthreads();
    for (int k = 0; k < NSLOTS; ++k) {
        unsigned long long lk = ~0ull; int li = -1;
        for (int t = tid; t < len; t += THREADS)
            if (keys[t] < lk) { lk = keys[t]; li = t; }
        skey[tid] = lk; sidx[tid] = li;
        __syncthreads();
        for (int s = THREADS / 2; s > 0; s >>= 1) {
            if (tid < s && skey[tid + s] < skey[tid]) {
                skey[tid] = skey[tid + s]; sidx[tid] = sidx[tid + s];
            }
            __syncthreads();
        }
        if (tid == 0) {
            unsigned long long best = skey[0];
            top26g[blockIdx.x * NSLOTS + k] = best;
            if (best != ~0ull) keys[sidx[0]] = ~0ull;   // remove winner
        }
        __syncthreads();
    }
}

// Phase B: one block merges NB*26 keys, writes root -> channel map.
__global__ __launch_bounds__(1024) void k_sel2(const unsigned long long* __restrict__ top26g,
                                               signed char* __restrict__ chan) {
    __shared__ unsigned long long keys[NB * NSLOTS];  // 3328 * 8 = 26.6 KB
    __shared__ unsigned long long skey[1024];
    __shared__ int sidx[1024];
    const int tid = threadIdx.x;
    const int NK = NB * NSLOTS;
    for (int t = tid; t < NK; t += 1024) keys[t] = top26g[t];
    __syncthreads();
    for (int k = 0; k < NSLOTS; ++k) {
        unsigned long long lk = ~0ull; int li = -1;
        for (int t = tid; t < NK; t += 1024)
            if (keys[t] < lk) { lk = keys[t]; li = t; }
        skey[tid] = lk; sidx[tid] = li;
        __syncthreads();
        for (int s = 512; s > 0; s >>= 1) {
            if (tid < s && skey[tid + s] < skey[tid]) {
                skey[tid] = skey[tid + s]; sidx[tid] = sidx[tid + s];
            }
            __syncthreads();
        }
        if (tid == 0) {
            unsigned long long best = skey[0];
            if (best != ~0ull) {
                chan[(unsigned int)(best & 0xFFFFFFFFull)] = (signed char)k;
                keys[sidx[0]] = ~0ull;
            }
        }
        __syncthreads();
    }
}

// one-hot 26xHxW int32 output, int4 stores
__global__ __launch_bounds__(THREADS) void k_output(const int* __restrict__ labfull,
                                                    const signed char* __restrict__ chan,
                                                    int* __restrict__ out) {
    int i4 = (blockIdx.x * THREADS + threadIdx.x) * 4;
    int chv[4];
    #pragma unroll
    for (int t = 0; t < 4; ++t) {
        int lab = labfull[i4 + t];
        chv[t] = (lab < BIGL) ? (int)chan[lab] : -1;
    }
    #pragma unroll
    for (int c = 0; c < NSLOTS; ++c) {
        int4 v;
        v.x = (chv[0] == c) ? 1 : 0;
        v.y = (chv[1] == c) ? 1 : 0;
        v.z = (chv[2] == c) ? 1 : 0;
        v.w = (chv[3] == c) ? 1 : 0;
        *(int4*)(out + (size_t)c * HWN + i4) = v;
    }
}

extern "C" void kernel_launch(void* const* d_in, const int* in_sizes, int n_in,
                              void* d_out, int out_size, void* d_ws, size_t ws_size,
                              hipStream_t stream) {
    const float* mask = (const float*)d_in[0];
    int* out = (int*)d_out;

    char* w = (char*)d_ws;
    int* parent                 = (int*)(w);                          //  8 MB
    int* labfull                = (int*)(w + (size_t)HWN * 4);        //  8 MB
    int* sizes                  = (int*)(w + (size_t)HWN * 8);        //  8 MB
    unsigned long long* colsum  = (unsigned long long*)(w + (size_t)HWN * 12); // 16 MB
    uint8_t* flags              = (uint8_t*)(w + (size_t)HWN * 20);   //  2 MB
    signed char* chan           = (signed char*)(w + (size_t)HWN * 21); // 2 MB
    int* cand                   = (int*)(w + (size_t)HWN * 22);       // 280 KB
    int* counter                = (int*)(w + (size_t)HWN * 22 + MAXCAND * 4);
    unsigned long long* top26g  = (unsigned long long*)(w + (size_t)HWN * 22 + MAXCAND * 4 + 256);

    // ws is re-poisoned 0xAA before every call — re-init what we accumulate into
    hipMemsetAsync(sizes, 0, (size_t)HWN * 4, stream);
    hipMemsetAsync(colsum, 0, (size_t)HWN * 8, stream);
    hipMemsetAsync(chan, 0xFF, (size_t)HWN, stream);    // -1 = no channel
    hipMemsetAsync(counter, 0, 4, stream);

    const int blocks = HWN / THREADS;   // 8192
    k_local       <<<NTILES, THREADS, 0, stream>>>(mask, flags, parent);
    k_merge       <<<NTILES, THREADS, 0, stream>>>(flags, parent);
    k_border_stats<<<blocks, THREADS, 0, stream>>>(flags, parent, labfull, sizes, colsum,
                                                   cand, counter);
    k_sel1        <<<NB, THREADS, 0, stream>>>(cand, counter, sizes, colsum, top26g);
    k_sel2        <<<1, 1024, 0, stream>>>(top26g, chan);
    k_output      <<<HWN / (4 * THREADS), THREADS, 0, stream>>>(labfull, chan, out);
}

// Round 9
// 416.020 us; speedup vs baseline: 2.8495x; 1.0492x over previous
//
#include <hip/hip_runtime.h>
#include <stdint.h>

#define HH 1024
#define WW 2048
#define HWN (HH*WW)          // 2097152
#define BIGL HWN             // 'no cluster' sentinel
#define NSLOTS 26
#define MINCL 30
#define THREADS 256
#define LTHREADS 512         // k_local block size (8 waves)
#define MAXCAND 70000        // >= HWN/30 + 1 (2M/30 = 69906 max possible)
#define HSZ 512              // per-block LDS label-hash entries
#define TILE 4096            // 64x64 tile
#define NTILES 512           // (1024/64)*(2048/64)
#define NB 128               // phase-A selection blocks

typedef int vi4 __attribute__((ext_vector_type(4)));

// ---------------- global union-find (lock-free, min-root) ----------------
__device__ __forceinline__ int uf_load(int* p, int i) {
    return __hip_atomic_load(&p[i], __ATOMIC_RELAXED, __HIP_MEMORY_SCOPE_AGENT);
}
__device__ __forceinline__ void uf_store(int* p, int i, int v) {
    __hip_atomic_store(&p[i], v, __ATOMIC_RELAXED, __HIP_MEMORY_SCOPE_AGENT);
}
__device__ int uf_find(int* parent, int x) {
    int p = uf_load(parent, x);
    while (p != x) {
        int gp = uf_load(parent, p);
        if (gp != p) uf_store(parent, x, gp);   // path halving (benign race)
        x = p; p = gp;
    }
    return p;
}
__device__ void uf_union(int* parent, int a, int b) {
    int ra = uf_find(parent, a);
    int rb = uf_find(parent, b);
    while (ra != rb) {
        if (ra > rb) { int t = ra; ra = rb; rb = t; }   // hook larger under smaller
        int old = atomicCAS(&parent[rb], rb, ra);
        if (old == rb) return;
        rb = uf_find(parent, old);
        ra = uf_find(parent, ra);
    }
}

// ---------------- LDS union-find (block-local, min-root) ----------------
__device__ __forceinline__ int l_load(int* p, int i) {
    return __hip_atomic_load(&p[i], __ATOMIC_RELAXED, __HIP_MEMORY_SCOPE_WORKGROUP);
}
__device__ __forceinline__ void l_store(int* p, int i, int v) {
    __hip_atomic_store(&p[i], v, __ATOMIC_RELAXED, __HIP_MEMORY_SCOPE_WORKGROUP);
}
__device__ int l_find(int* lp, int x) {
    int p = l_load(lp, x);
    while (p != x) {
        int gp = l_load(lp, p);
        if (gp != p) l_store(lp, x, gp);
        x = p; p = gp;
    }
    return p;
}
__device__ void l_union(int* lp, int a, int b) {
    int ra = l_find(lp, a);
    int rb = l_find(lp, b);
    while (ra != rb) {
        if (ra > rb) { int t = ra; ra = rb; rb = t; }
        int old = atomicCAS(&lp[rb], rb, ra);
        if (old == rb) return;
        rb = l_find(lp, old);
        ra = l_find(lp, ra);
    }
}

// ---------------- fused init + per-tile CC + ws zeroing ----------------
__global__ __launch_bounds__(LTHREADS) void k_local(const float* __restrict__ mask,
                                                    uint8_t* __restrict__ flags,
                                                    int* __restrict__ parent,
                                                    int* __restrict__ sizes,
                                                    unsigned long long* __restrict__ colsum,
                                                    signed char* __restrict__ chan,
                                                    int* __restrict__ counter) {
    __shared__ uint8_t lact[66 * 72];   // halo active map, row stride 72
    __shared__ uint8_t lc8[TILE];
    __shared__ int lp[TILE];
    const int tid = threadIdx.x;
    int tile_x = blockIdx.x & 31, tile_y = blockIdx.x >> 5;
    int r0 = tile_y << 6, c0 = tile_x << 6;

    // zero this block's 1/512 slice of sizes/colsum/chan (+counter once).
    // Kernel boundary before k_border_stats makes these visible.
    {
        int base = blockIdx.x * (HWN / NTILES);      // 4096 elements
        vi4* sz4 = (vi4*)(sizes + base);
        vi4* cs4 = (vi4*)(colsum + base);            // 4096 u64 = 8192 int = 2048 vi4
        for (int t = tid; t < 1024; t += LTHREADS) sz4[t] = (vi4)0;
        for (int t = tid; t < 2048; t += LTHREADS) cs4[t] = (vi4)0;
        vi4* ch4 = (vi4*)(chan + base);              // 4096 bytes = 256 vi4
        for (int t = tid; t < 256; t += LTHREADS) ch4[t] = (vi4)(-1);
        if (blockIdx.x == 0 && tid == 0) *counter = 0;
    }

    {   // stage halo
        int tx = tid & 15, ty = tid >> 4;            // 32 rows of 16 threads
        for (int yy = ty; yy < 66; yy += 32) {
            int gr = r0 - 1 + yy;
            for (int xx = tx; xx < 66; xx += 16) {
                int gc = c0 - 1 + xx;
                bool a = false;
                if ((unsigned)gr < HH && (unsigned)gc < WW)
                    a = mask[gr * WW + gc] > 0.1f;
                lact[yy * 72 + xx] = a ? 1 : 0;
            }
        }
    }
    __syncthreads();
    for (int li = tid; li < TILE; li += LTHREADS) {
        int lr = li >> 6, lc = li & 63;
        int b = (lr + 1) * 72 + (lc + 1);
        int a = lact[b];
        int cnt = lact[b - 73] + lact[b - 72] + lact[b - 71]
                + lact[b - 1]  + a           + lact[b + 1]
                + lact[b + 71] + lact[b + 72] + lact[b + 73];
        lc8[li] = (uint8_t)(a | ((a && cnt >= 4) ? 2 : 0));  // MIN_SAMPLES=4 incl self
        lp[li] = li;
    }
    __syncthreads();
    if (tid < 256) {   // flags -> global, 16B per thread
        int row = tid >> 2, chunk = tid & 3;
        ((uint4*)(flags + (size_t)(r0 + row) * WW + c0))[chunk] =
            ((const uint4*)lc8)[row * 4 + chunk];
    }
    for (int li = tid; li < TILE; li += LTHREADS) {
        if (!(lc8[li] & 2)) continue;
        int lr = li >> 6, lc = li & 63;
        if (lc > 0 && (lc8[li - 1] & 2)) l_union(lp, li, li - 1);
        if (lr > 0) {
            if (lc > 0  && (lc8[li - 65] & 2)) l_union(lp, li, li - 65);
            if (           (lc8[li - 64] & 2)) l_union(lp, li, li - 64);
            if (lc < 63 && (lc8[li - 63] & 2)) l_union(lp, li, li - 63);
        }
    }
    __syncthreads();
    for (int li = tid; li < TILE; li += LTHREADS) {
        if (!(lc8[li] & 2)) continue;
        int root = li, p;
        while ((p = lp[root]) != root) root = p;   // lp stable after barrier
        int gi = (r0 + (li >> 6)) * WW + c0 + (li & 63);
        int gr = (r0 + (root >> 6)) * WW + c0 + (root & 63);
        parent[gi] = gr;
    }
}

// union only tile-crossing edges (R5-identical)
__global__ __launch_bounds__(THREADS) void k_merge(const uint8_t* __restrict__ flags,
                                                   int* __restrict__ parent) {
    int tile_x = blockIdx.x & 31, tile_y = blockIdx.x >> 5;
    int r0 = tile_y << 6, c0 = tile_x << 6;
    int t = threadIdx.x;
    int lane = t & 63;

    if (t < 64) {                                    // top row, lr=0, lc=t
        int r = r0, c = c0 + t, i = r * WW + c;
        bool selfC = (flags[i] & 2) != 0;
        bool nC = false, nwC = false, neC = false;
        if (selfC && r > 0) {
            nC  = (flags[i - WW] & 2) != 0;
            nwC = (c > 0)      && (flags[i - WW - 1] & 2);
            neC = (c < WW - 1) && (flags[i - WW + 1] & 2);
        }
        int did = 0, ra = -1, rb = -1;
        if (selfC && r > 0 && nC) { ra = uf_find(parent, i); rb = uf_find(parent, i - WW); did = 1; }
        int pra = __shfl_up(ra, 1), prb = __shfl_up(rb, 1), pdid = __shfl_up(did, 1);
        bool head = (lane == 0) || !pdid || pra != ra || prb != rb;
        if (did && head) uf_union(parent, ra, rb);
        if (selfC && r > 0) {
            if (t == 0) {
                if (nwC) uf_union(parent, i, i - WW - 1);          // diag tile
                if (!nC && neC) uf_union(parent, i, i - WW + 1);
            } else if (t == 63) {
                if (!nC && nwC) uf_union(parent, i, i - WW - 1);
                if (neC) {
                    bool eC = (c < WW - 1) && (flags[i + 1] & 2);
                    if (!eC) uf_union(parent, i, i - WW + 1);
                    // else: us~E (right tile corner W-edge) and E~NE (its N-edge)
                }
            } else if (!nC) {
                if (nwC) uf_union(parent, i, i - WW - 1);
                if (neC) uf_union(parent, i, i - WW + 1);
            }
        }
        if (t == 0 && selfC && c > 0 && (flags[i - 1] & 2))        // corner W edge
            uf_union(parent, i, i - 1);
    } else if (t < 127) {                            // left col, lr=1..63, lc=0
        int lr = t - 63;
        int r = r0 + lr, c = c0, i = r * WW + c;
        bool selfC = (flags[i] & 2) != 0;
        bool wC = false, nwC = false;
        if (selfC && c > 0) {
            wC  = (flags[i - 1] & 2) != 0;
            nwC = (flags[i - WW - 1] & 2) != 0;      // r >= 1 guaranteed (lr>=1)
        }
        int did = 0, ra = -1, rb = -1;
        if (selfC && wC) { ra = uf_find(parent, i); rb = uf_find(parent, i - 1); did = 1; }
        int pra = __shfl_up(ra, 1), prb = __shfl_up(rb, 1), pdid = __shfl_up(did, 1);
        bool head = (lane == 0) || !pdid || pra != ra || prb != rb;
        if (did && head) uf_union(parent, ra, rb);
        if (selfC && !wC && nwC) uf_union(parent, i, i - WW - 1);  // if wC: NW~W local in left tile
    } else if (t < 190) {                            // right col, lr=1..63, lc=63
        int lr = t - 126;
        int r = r0 + lr, c = c0 + 63, i = r * WW + c;
        bool selfC = (flags[i] & 2) != 0;
        if (selfC && c < WW - 1) {
            bool neC = (flags[i - WW + 1] & 2) != 0;
            bool eC  = (flags[i + 1] & 2) != 0;
            if (neC && !eC) uf_union(parent, i, i - WW + 1);
            // if eC: us~E (right tile W-edge) and E~NE (right tile local N-edge)
        }
    }
}

// border assignment + per-label stats via on-the-fly uf_find (R8-identical)
__global__ __launch_bounds__(THREADS) void k_border_stats(
        const uint8_t* __restrict__ flags, int* __restrict__ parent,
        int* __restrict__ labfull, int* __restrict__ sizes,
        unsigned long long* __restrict__ colsum,
        int* __restrict__ cand, int* __restrict__ counter) {
    __shared__ int h_lab[HSZ];
    __shared__ int h_sz[HSZ];
    __shared__ unsigned long long h_cs[HSZ];
    for (int t = threadIdx.x; t < HSZ; t += THREADS) {
        h_lab[t] = -1; h_sz[t] = 0; h_cs[t] = 0;
    }
    __syncthreads();

    int i = blockIdx.x * THREADS + threadIdx.x;
    int f = flags[i];
    int lab = BIGL;
    if (f & 2) {
        lab = uf_find(parent, i);
    } else if (f & 1) {              // active non-core: min core-neighbor root in 3x3
        int r = i >> 11, c = i & (WW - 1);
        int m = BIGL;
        #pragma unroll
        for (int dr = -1; dr <= 1; ++dr) {
            int rr = r + dr;
            if (rr < 0 || rr >= HH) continue;
            #pragma unroll
            for (int dc = -1; dc <= 1; ++dc) {
                int cc = c + dc;
                if (cc < 0 || cc >= WW) continue;
                int n = rr * WW + cc;
                if (flags[n] & 2) {
                    int v = uf_find(parent, n);
                    if (v < m) m = v;
                }
            }
        }
        lab = m;                     // BIGL if no core neighbor
    }
    labfull[i] = lab;

    // wave-level run aggregation (WW % 64 == 0: wave never crosses a row)
    int lane = threadIdx.x & 63;
    int labp = __shfl_up(lab, 1);
    bool head = (lane == 0) || (labp != lab);
    unsigned long long hm = __ballot(head);
    if (head && lab < BIGL) {
        unsigned long long rest = (hm >> lane) >> 1;
        int len = rest ? __ffsll((unsigned long long)rest) : (64 - lane);
        long long c0 = (long long)(i & (WW - 1));
        unsigned long long csum =
            (unsigned long long)(c0 * len + (long long)len * (len - 1) / 2);
        unsigned slot = (((unsigned)lab * 2654435761u) >> 20) & (HSZ - 1);
        for (;;) {
            int old = atomicCAS(&h_lab[slot], -1, lab);
            if (old == -1 || old == lab) {
                atomicAdd(&h_sz[slot], len);
                atomicAdd(&h_cs[slot], csum);
                break;
            }
            slot = (slot + 1) & (HSZ - 1);
        }
    }
    __syncthreads();
    for (int t = threadIdx.x; t < HSZ; t += THREADS) {
        int lb = h_lab[t];
        if (lb >= 0) {
            int add = h_sz[t];
            int old = atomicAdd(&sizes[lb], add);
            if (old < MINCL && old + add >= MINCL) {   // exactly one block sees this
                int p = atomicAdd(counter, 1);
                cand[p] = lb;
            }
            atomicAdd(&colsum[lb], h_cs[t]);
        }
    }
}

// ---- two-phase parallel top-26 selection (R8-proven) ----
__global__ __launch_bounds__(THREADS) void k_sel1(const int* __restrict__ cand,
                                                  const int* __restrict__ counter,
                                                  const int* __restrict__ sizes,
                                                  const unsigned long long* __restrict__ colsum,
                                                  unsigned long long* __restrict__ top26g) {
    __shared__ unsigned long long keys[1024];
    __shared__ unsigned long long skey[THREADS];
    __shared__ int sidx[THREADS];
    const int tid = threadIdx.x;
    int n = *counter;
    int slice = (n + NB - 1) / NB;
    if (slice > 1024) slice = 1024;
    int j0 = blockIdx.x * slice;
    int j1 = j0 + slice; if (j1 > n) j1 = n;
    int len = j1 - j0; if (len < 0) len = 0;
    for (int t = tid; t < len; t += THREADS) {
        int lab = cand[j0 + t];
        float mean = (float)colsum[lab] / (float)sizes[lab];
        keys[t] = ((unsigned long long)__float_as_uint(mean) << 32) | (unsigned int)lab;
    }
    __syncthreads();
    for (int k = 0; k < NSLOTS; ++k) {
        unsigned long long lk = ~0ull; int li = -1;
        for (int t = tid; t < len; t += THREADS)
            if (keys[t] < lk) { lk = keys[t]; li = t; }
        skey[tid] = lk; sidx[tid] = li;
        __syncthreads();
        for (int s = THREADS / 2; s > 0; s >>= 1) {
            if (tid < s && skey[tid + s] < skey[tid]) {
                skey[tid] = skey[tid + s]; sidx[tid] = sidx[tid + s];
            }
            __syncthreads();
        }
        if (tid == 0) {
            unsigned long long best = skey[0];
            top26g[blockIdx.x * NSLOTS + k] = best;
            if (best != ~0ull) keys[sidx[0]] = ~0ull;   // remove winner
        }
        __syncthreads();
    }
}

__global__ __launch_bounds__(1024) void k_sel2(const unsigned long long* __restrict__ top26g,
                                               signed char* __restrict__ chan) {
    __shared__ unsigned long long keys[NB * NSLOTS];  // 3328 * 8 = 26.6 KB
    __shared__ unsigned long long skey[1024];
    __shared__ int sidx[1024];
    const int tid = threadIdx.x;
    const int NK = NB * NSLOTS;
    for (int t = tid; t < NK; t += 1024) keys[t] = top26g[t];
    __syncthreads();
    for (int k = 0; k < NSLOTS; ++k) {
        unsigned long long lk = ~0ull; int li = -1;
        for (int t = tid; t < NK; t += 1024)
            if (keys[t] < lk) { lk = keys[t]; li = t; }
        skey[tid] = lk; sidx[tid] = li;
        __syncthreads();
        for (int s = 512; s > 0; s >>= 1) {
            if (tid < s && skey[tid + s] < skey[tid]) {
                skey[tid] = skey[tid + s]; sidx[tid] = sidx[tid + s];
            }
            __syncthreads();
        }
        if (tid == 0) {
            unsigned long long best = skey[0];
            if (best != ~0ull) {
                chan[(unsigned int)(best & 0xFFFFFFFFull)] = (signed char)k;
                keys[sidx[0]] = ~0ull;
            }
        }
        __syncthreads();
    }
}

// one-hot 26xHxW int32 output, non-temporal int4 stores
__global__ __launch_bounds__(THREADS) void k_output(const int* __restrict__ labfull,
                                                    const signed char* __restrict__ chan,
                                                    int* __restrict__ out) {
    int i4 = (blockIdx.x * THREADS + threadIdx.x) * 4;
    int chv[4];
    #pragma unroll
    for (int t = 0; t < 4; ++t) {
        int lab = labfull[i4 + t];
        chv[t] = (lab < BIGL) ? (int)chan[lab] : -1;
    }
    #pragma unroll
    for (int c = 0; c < NSLOTS; ++c) {
        vi4 v;
        v.x = (chv[0] == c) ? 1 : 0;
        v.y = (chv[1] == c) ? 1 : 0;
        v.z = (chv[2] == c) ? 1 : 0;
        v.w = (chv[3] == c) ? 1 : 0;
        __builtin_nontemporal_store(v, (vi4*)(out + (size_t)c * HWN + i4));
    }
}

extern "C" void kernel_launch(void* const* d_in, const int* in_sizes, int n_in,
                              void* d_out, int out_size, void* d_ws, size_t ws_size,
                              hipStream_t stream) {
    const float* mask = (const float*)d_in[0];
    int* out = (int*)d_out;

    char* w = (char*)d_ws;
    int* parent                 = (int*)(w);                          //  8 MB
    int* labfull                = (int*)(w + (size_t)HWN * 4);        //  8 MB
    int* sizes                  = (int*)(w + (size_t)HWN * 8);        //  8 MB
    unsigned long long* colsum  = (unsigned long long*)(w + (size_t)HWN * 12); // 16 MB
    uint8_t* flags              = (uint8_t*)(w + (size_t)HWN * 20);   //  2 MB
    signed char* chan           = (signed char*)(w + (size_t)HWN * 21); // 2 MB
    int* cand                   = (int*)(w + (size_t)HWN * 22);       // 280 KB
    int* counter                = (int*)(w + (size_t)HWN * 22 + MAXCAND * 4);
    unsigned long long* top26g  = (unsigned long long*)(w + (size_t)HWN * 22 + MAXCAND * 4 + 256);

    // no memsets: k_local zeros sizes/colsum/chan/counter (kernel-boundary
    // visibility before k_border_stats consumes them)
    const int blocks = HWN / THREADS;   // 8192
    k_local       <<<NTILES, LTHREADS, 0, stream>>>(mask, flags, parent,
                                                    sizes, colsum, chan, counter);
    k_merge       <<<NTILES, THREADS, 0, stream>>>(flags, parent);
    k_border_stats<<<blocks, THREADS, 0, stream>>>(flags, parent, labfull, sizes, colsum,
                                                   cand, counter);
    k_sel1        <<<NB, THREADS, 0, stream>>>(cand, counter, sizes, colsum, top26g);
    k_sel2        <<<1, 1024, 0, stream>>>(top26g, chan);
    k_output      <<<HWN / (4 * THREADS), THREADS, 0, stream>>>(labfull, chan, out);
}

// Round 10
// 405.367 us; speedup vs baseline: 2.9243x; 1.0263x over previous
//
#include <hip/hip_runtime.h>
#include <stdint.h>

#define HH 1024
#define WW 2048
#define HWN (HH*WW)          // 2097152
#define BIGL HWN             // 'no cluster' sentinel
#define NSLOTS 26
#define MINCL 30
#define THREADS 256
#define LTHREADS 512         // k_local block size (8 waves)
#define MAXCAND 70000        // >= HWN/30 + 1 (2M/30 = 69906 max possible)
#define HSZ 512              // per-block LDS label-hash entries
#define TILE 4096            // 64x64 tile
#define NTILES 512           // (1024/64)*(2048/64)
#define NB 128               // selection blocks; NB*slice covers MAXCAND

typedef int vi4 __attribute__((ext_vector_type(4)));
typedef unsigned long long u64;

// ---------------- global union-find (lock-free, min-root) ----------------
__device__ __forceinline__ int uf_load(int* p, int i) {
    return __hip_atomic_load(&p[i], __ATOMIC_RELAXED, __HIP_MEMORY_SCOPE_AGENT);
}
__device__ __forceinline__ void uf_store(int* p, int i, int v) {
    __hip_atomic_store(&p[i], v, __ATOMIC_RELAXED, __HIP_MEMORY_SCOPE_AGENT);
}
__device__ int uf_find(int* parent, int x) {
    int p = uf_load(parent, x);
    while (p != x) {
        int gp = uf_load(parent, p);
        if (gp != p) uf_store(parent, x, gp);   // path halving (benign race)
        x = p; p = gp;
    }
    return p;
}
__device__ void uf_union(int* parent, int a, int b) {
    int ra = uf_find(parent, a);
    int rb = uf_find(parent, b);
    while (ra != rb) {
        if (ra > rb) { int t = ra; ra = rb; rb = t; }   // hook larger under smaller
        int old = atomicCAS(&parent[rb], rb, ra);
        if (old == rb) return;
        rb = uf_find(parent, old);
        ra = uf_find(parent, ra);
    }
}

// ---------------- LDS union-find (block-local, min-root) ----------------
__device__ __forceinline__ int l_load(int* p, int i) {
    return __hip_atomic_load(&p[i], __ATOMIC_RELAXED, __HIP_MEMORY_SCOPE_WORKGROUP);
}
__device__ __forceinline__ void l_store(int* p, int i, int v) {
    __hip_atomic_store(&p[i], v, __ATOMIC_RELAXED, __HIP_MEMORY_SCOPE_WORKGROUP);
}
__device__ int l_find(int* lp, int x) {
    int p = l_load(lp, x);
    while (p != x) {
        int gp = l_load(lp, p);
        if (gp != p) l_store(lp, x, gp);
        x = p; p = gp;
    }
    return p;
}
__device__ void l_union(int* lp, int a, int b) {
    int ra = l_find(lp, a);
    int rb = l_find(lp, b);
    while (ra != rb) {
        if (ra > rb) { int t = ra; ra = rb; rb = t; }
        int old = atomicCAS(&lp[rb], rb, ra);
        if (old == rb) return;
        rb = l_find(lp, old);
        ra = l_find(lp, ra);
    }
}

// ---------------- fused init + per-tile CC + ws zeroing (R9-identical) ----------------
__global__ __launch_bounds__(LTHREADS) void k_local(const float* __restrict__ mask,
                                                    uint8_t* __restrict__ flags,
                                                    int* __restrict__ parent,
                                                    int* __restrict__ sizes,
                                                    unsigned long long* __restrict__ colsum,
                                                    signed char* __restrict__ chan,
                                                    int* __restrict__ counter) {
    __shared__ uint8_t lact[66 * 72];   // halo active map, row stride 72
    __shared__ uint8_t lc8[TILE];
    __shared__ int lp[TILE];
    const int tid = threadIdx.x;
    int tile_x = blockIdx.x & 31, tile_y = blockIdx.x >> 5;
    int r0 = tile_y << 6, c0 = tile_x << 6;

    {   // zero this block's 1/512 slice of sizes/colsum/chan (+counter/done once)
        int base = blockIdx.x * (HWN / NTILES);      // 4096 elements
        vi4* sz4 = (vi4*)(sizes + base);
        vi4* cs4 = (vi4*)(colsum + base);
        for (int t = tid; t < 1024; t += LTHREADS) sz4[t] = (vi4)0;
        for (int t = tid; t < 2048; t += LTHREADS) cs4[t] = (vi4)0;
        vi4* ch4 = (vi4*)(chan + base);
        for (int t = tid; t < 256; t += LTHREADS) ch4[t] = (vi4)(-1);
        if (blockIdx.x == 0 && tid == 0) { counter[0] = 0; counter[1] = 0; }
    }

    {   // stage halo
        int tx = tid & 15, ty = tid >> 4;
        for (int yy = ty; yy < 66; yy += 32) {
            int gr = r0 - 1 + yy;
            for (int xx = tx; xx < 66; xx += 16) {
                int gc = c0 - 1 + xx;
                bool a = false;
                if ((unsigned)gr < HH && (unsigned)gc < WW)
                    a = mask[gr * WW + gc] > 0.1f;
                lact[yy * 72 + xx] = a ? 1 : 0;
            }
        }
    }
    __syncthreads();
    for (int li = tid; li < TILE; li += LTHREADS) {
        int lr = li >> 6, lc = li & 63;
        int b = (lr + 1) * 72 + (lc + 1);
        int a = lact[b];
        int cnt = lact[b - 73] + lact[b - 72] + lact[b - 71]
                + lact[b - 1]  + a           + lact[b + 1]
                + lact[b + 71] + lact[b + 72] + lact[b + 73];
        lc8[li] = (uint8_t)(a | ((a && cnt >= 4) ? 2 : 0));  // MIN_SAMPLES=4 incl self
        lp[li] = li;
    }
    __syncthreads();
    if (tid < 256) {   // flags -> global, 16B per thread
        int row = tid >> 2, chunk = tid & 3;
        ((uint4*)(flags + (size_t)(r0 + row) * WW + c0))[chunk] =
            ((const uint4*)lc8)[row * 4 + chunk];
    }
    for (int li = tid; li < TILE; li += LTHREADS) {
        if (!(lc8[li] & 2)) continue;
        int lr = li >> 6, lc = li & 63;
        if (lc > 0 && (lc8[li - 1] & 2)) l_union(lp, li, li - 1);
        if (lr > 0) {
            if (lc > 0  && (lc8[li - 65] & 2)) l_union(lp, li, li - 65);
            if (           (lc8[li - 64] & 2)) l_union(lp, li, li - 64);
            if (lc < 63 && (lc8[li - 63] & 2)) l_union(lp, li, li - 63);
        }
    }
    __syncthreads();
    for (int li = tid; li < TILE; li += LTHREADS) {
        if (!(lc8[li] & 2)) continue;
        int root = li, p;
        while ((p = lp[root]) != root) root = p;   // lp stable after barrier
        int gi = (r0 + (li >> 6)) * WW + c0 + (li & 63);
        int gr = (r0 + (root >> 6)) * WW + c0 + (root & 63);
        parent[gi] = gr;
    }
}

// union only tile-crossing edges (R9-identical)
__global__ __launch_bounds__(THREADS) void k_merge(const uint8_t* __restrict__ flags,
                                                   int* __restrict__ parent) {
    int tile_x = blockIdx.x & 31, tile_y = blockIdx.x >> 5;
    int r0 = tile_y << 6, c0 = tile_x << 6;
    int t = threadIdx.x;
    int lane = t & 63;

    if (t < 64) {                                    // top row, lr=0, lc=t
        int r = r0, c = c0 + t, i = r * WW + c;
        bool selfC = (flags[i] & 2) != 0;
        bool nC = false, nwC = false, neC = false;
        if (selfC && r > 0) {
            nC  = (flags[i - WW] & 2) != 0;
            nwC = (c > 0)      && (flags[i - WW - 1] & 2);
            neC = (c < WW - 1) && (flags[i - WW + 1] & 2);
        }
        int did = 0, ra = -1, rb = -1;
        if (selfC && r > 0 && nC) { ra = uf_find(parent, i); rb = uf_find(parent, i - WW); did = 1; }
        int pra = __shfl_up(ra, 1), prb = __shfl_up(rb, 1), pdid = __shfl_up(did, 1);
        bool head = (lane == 0) || !pdid || pra != ra || prb != rb;
        if (did && head) uf_union(parent, ra, rb);
        if (selfC && r > 0) {
            if (t == 0) {
                if (nwC) uf_union(parent, i, i - WW - 1);          // diag tile
                if (!nC && neC) uf_union(parent, i, i - WW + 1);
            } else if (t == 63) {
                if (!nC && nwC) uf_union(parent, i, i - WW - 1);
                if (neC) {
                    bool eC = (c < WW - 1) && (flags[i + 1] & 2);
                    if (!eC) uf_union(parent, i, i - WW + 1);
                }
            } else if (!nC) {
                if (nwC) uf_union(parent, i, i - WW - 1);
                if (neC) uf_union(parent, i, i - WW + 1);
            }
        }
        if (t == 0 && selfC && c > 0 && (flags[i - 1] & 2))        // corner W edge
            uf_union(parent, i, i - 1);
    } else if (t < 127) {                            // left col, lr=1..63, lc=0
        int lr = t - 63;
        int r = r0 + lr, c = c0, i = r * WW + c;
        bool selfC = (flags[i] & 2) != 0;
        bool wC = false, nwC = false;
        if (selfC && c > 0) {
            wC  = (flags[i - 1] & 2) != 0;
            nwC = (flags[i - WW - 1] & 2) != 0;
        }
        int did = 0, ra = -1, rb = -1;
        if (selfC && wC) { ra = uf_find(parent, i); rb = uf_find(parent, i - 1); did = 1; }
        int pra = __shfl_up(ra, 1), prb = __shfl_up(rb, 1), pdid = __shfl_up(did, 1);
        bool head = (lane == 0) || !pdid || pra != ra || prb != rb;
        if (did && head) uf_union(parent, ra, rb);
        if (selfC && !wC && nwC) uf_union(parent, i, i - WW - 1);
    } else if (t < 190) {                            // right col, lr=1..63, lc=63
        int lr = t - 126;
        int r = r0 + lr, c = c0 + 63, i = r * WW + c;
        bool selfC = (flags[i] & 2) != 0;
        if (selfC && c < WW - 1) {
            bool neC = (flags[i - WW + 1] & 2) != 0;
            bool eC  = (flags[i + 1] & 2) != 0;
            if (neC && !eC) uf_union(parent, i, i - WW + 1);
        }
    }
}

// border assignment + per-label stats via on-the-fly uf_find (R9-identical)
__global__ __launch_bounds__(THREADS) void k_border_stats(
        const uint8_t* __restrict__ flags, int* __restrict__ parent,
        int* __restrict__ labfull, int* __restrict__ sizes,
        unsigned long long* __restrict__ colsum,
        int* __restrict__ cand, int* __restrict__ counter) {
    __shared__ int h_lab[HSZ];
    __shared__ int h_sz[HSZ];
    __shared__ unsigned long long h_cs[HSZ];
    for (int t = threadIdx.x; t < HSZ; t += THREADS) {
        h_lab[t] = -1; h_sz[t] = 0; h_cs[t] = 0;
    }
    __syncthreads();

    int i = blockIdx.x * THREADS + threadIdx.x;
    int f = flags[i];
    int lab = BIGL;
    if (f & 2) {
        lab = uf_find(parent, i);
    } else if (f & 1) {              // active non-core: min core-neighbor root in 3x3
        int r = i >> 11, c = i & (WW - 1);
        int m = BIGL;
        #pragma unroll
        for (int dr = -1; dr <= 1; ++dr) {
            int rr = r + dr;
            if (rr < 0 || rr >= HH) continue;
            #pragma unroll
            for (int dc = -1; dc <= 1; ++dc) {
                int cc = c + dc;
                if (cc < 0 || cc >= WW) continue;
                int n = rr * WW + cc;
                if (flags[n] & 2) {
                    int v = uf_find(parent, n);
                    if (v < m) m = v;
                }
            }
        }
        lab = m;                     // BIGL if no core neighbor
    }
    labfull[i] = lab;

    // wave-level run aggregation (WW % 64 == 0: wave never crosses a row)
    int lane = threadIdx.x & 63;
    int labp = __shfl_up(lab, 1);
    bool head = (lane == 0) || (labp != lab);
    unsigned long long hm = __ballot(head);
    if (head && lab < BIGL) {
        unsigned long long rest = (hm >> lane) >> 1;
        int len = rest ? __ffsll((unsigned long long)rest) : (64 - lane);
        long long c0 = (long long)(i & (WW - 1));
        unsigned long long csum =
            (unsigned long long)(c0 * len + (long long)len * (len - 1) / 2);
        unsigned slot = (((unsigned)lab * 2654435761u) >> 20) & (HSZ - 1);
        for (;;) {
            int old = atomicCAS(&h_lab[slot], -1, lab);
            if (old == -1 || old == lab) {
                atomicAdd(&h_sz[slot], len);
                atomicAdd(&h_cs[slot], csum);
                break;
            }
            slot = (slot + 1) & (HSZ - 1);
        }
    }
    __syncthreads();
    for (int t = threadIdx.x; t < HSZ; t += THREADS) {
        int lb = h_lab[t];
        if (lb >= 0) {
            int add = h_sz[t];
            int old = atomicAdd(&sizes[lb], add);
            if (old < MINCL && old + add >= MINCL) {   // exactly one block sees this
                int p = atomicAdd(counter, 1);
                cand[p] = lb;
            }
            atomicAdd(&colsum[lb], h_cs[t]);
        }
    }
}

// ---- fused single-kernel top-26 selection ----
// Wave-level register extraction (no barriers in the hot loop) + last-block
// final merge (atomic done-counter + threadfence; agent-scope reads).
__device__ __forceinline__ u64 wave_min_u64(u64 m) {
    #pragma unroll
    for (int off = 32; off; off >>= 1) {
        u64 o = __shfl_xor(m, off);
        if (o < m) m = o;
    }
    return m;
}

__global__ __launch_bounds__(THREADS) void k_sel(const int* __restrict__ cand,
                                                 int* __restrict__ counter,   // [0]=n, [1]=done
                                                 const int* __restrict__ sizes,
                                                 const unsigned long long* __restrict__ colsum,
                                                 unsigned long long* __restrict__ top26g,
                                                 signed char* __restrict__ chan) {
    __shared__ u64 wout[4 * NSLOTS];
    const int tid = threadIdx.x, lane = tid & 63, wv = tid >> 6;
    const int n = counter[0];
    int slice = (n + NB - 1) / NB;
    int j0 = blockIdx.x * slice;
    int j1 = j0 + slice; if (j1 > n) j1 = n;
    int len = j1 - j0; if (len < 0) len = 0;
    int chunk = (len + 3) >> 2;                 // per-wave share (<=137 for n<=70000)
    int s0 = j0 + wv * chunk;
    int s1 = s0 + chunk; if (s1 > j1) s1 = j1;

    // load this lane's keys (<=3) into registers
    u64 kk[3] = { ~0ull, ~0ull, ~0ull };
    #pragma unroll
    for (int t = 0; t < 3; ++t) {
        int j = s0 + lane + 64 * t;
        if (j < s1) {
            int lab = cand[j];
            float mean = (float)colsum[lab] / (float)sizes[lab];
            kk[t] = ((u64)__float_as_uint(mean) << 32) | (unsigned)lab;
        }
    }
    // wave-local top-26 (register exclusion, zero barriers)
    for (int k = 0; k < NSLOTS; ++k) {
        u64 m = kk[0]; int li = 0;
        if (kk[1] < m) { m = kk[1]; li = 1; }
        if (kk[2] < m) { m = kk[2]; li = 2; }
        u64 mpre = m;
        m = wave_min_u64(m);
        if (mpre == m && m != ~0ull) kk[li] = ~0ull;   // keys unique -> one winner
        if (lane == 0) wout[wv * NSLOTS + k] = m;
    }
    __syncthreads();
    // wave 0 merges the 104 wave winners; tid 0 writes block result to global
    if (wv == 0) {
        u64 a = (lane < 4 * NSLOTS) ? wout[lane] : ~0ull;
        u64 b = (lane + 64 < 4 * NSLOTS) ? wout[lane + 64] : ~0ull;
        for (int k = 0; k < NSLOTS; ++k) {
            u64 m = a < b ? a : b; int li = a < b ? 0 : 1;
            u64 mpre = m;
            m = wave_min_u64(m);
            if (mpre == m && m != ~0ull) { if (li == 0) a = ~0ull; else b = ~0ull; }
            if (lane == 0) top26g[blockIdx.x * NSLOTS + k] = m;
        }
    }
    __syncthreads();
    // last block performs the final merge (tid 0 wrote this block's top26g)
    __shared__ int lastflag;
    if (tid == 0) {
        __threadfence();                                // release top26g writes
        lastflag = (atomicAdd(&counter[1], 1) == NB - 1);
    }
    __syncthreads();
    if (!lastflag) return;

    // read all NB*26 = 3328 keys (13 per lane per wave), agent-scope loads
    u64 mk[13];
    #pragma unroll
    for (int t = 0; t < 13; ++t) {
        int j = wv * 832 + lane + 64 * t;               // 4 waves x 832 = 3328
        mk[t] = __hip_atomic_load(&top26g[j], __ATOMIC_RELAXED, __HIP_MEMORY_SCOPE_AGENT);
    }
    for (int k = 0; k < NSLOTS; ++k) {
        u64 m = mk[0]; int li = 0;
        #pragma unroll
        for (int t = 1; t < 13; ++t) if (mk[t] < m) { m = mk[t]; li = t; }
        u64 mpre = m;
        m = wave_min_u64(m);
        if (mpre == m && m != ~0ull) mk[li] = ~0ull;
        if (lane == 0) wout[wv * NSLOTS + k] = m;
    }
    __syncthreads();
    if (wv == 0) {
        u64 a = (lane < 4 * NSLOTS) ? wout[lane] : ~0ull;
        u64 b = (lane + 64 < 4 * NSLOTS) ? wout[lane + 64] : ~0ull;
        for (int k = 0; k < NSLOTS; ++k) {
            u64 m = a < b ? a : b; int li = a < b ? 0 : 1;
            u64 mpre = m;
            m = wave_min_u64(m);
            if (mpre == m && m != ~0ull) { if (li == 0) a = ~0ull; else b = ~0ull; }
            if (lane == 0 && m != ~0ull)
                chan[(unsigned int)(m & 0xFFFFFFFFull)] = (signed char)k;
        }
    }
}

// one-hot 26xHxW int32 output, non-temporal int4 stores (R9-identical)
__global__ __launch_bounds__(THREADS) void k_output(const int* __restrict__ labfull,
                                                    const signed char* __restrict__ chan,
                                                    int* __restrict__ out) {
    int i4 = (blockIdx.x * THREADS + threadIdx.x) * 4;
    int chv[4];
    #pragma unroll
    for (int t = 0; t < 4; ++t) {
        int lab = labfull[i4 + t];
        chv[t] = (lab < BIGL) ? (int)chan[lab] : -1;
    }
    #pragma unroll
    for (int c = 0; c < NSLOTS; ++c) {
        vi4 v;
        v.x = (chv[0] == c) ? 1 : 0;
        v.y = (chv[1] == c) ? 1 : 0;
        v.z = (chv[2] == c) ? 1 : 0;
        v.w = (chv[3] == c) ? 1 : 0;
        __builtin_nontemporal_store(v, (vi4*)(out + (size_t)c * HWN + i4));
    }
}

extern "C" void kernel_launch(void* const* d_in, const int* in_sizes, int n_in,
                              void* d_out, int out_size, void* d_ws, size_t ws_size,
                              hipStream_t stream) {
    const float* mask = (const float*)d_in[0];
    int* out = (int*)d_out;

    char* w = (char*)d_ws;
    int* parent                 = (int*)(w);                          //  8 MB
    int* labfull                = (int*)(w + (size_t)HWN * 4);        //  8 MB
    int* sizes                  = (int*)(w + (size_t)HWN * 8);        //  8 MB
    unsigned long long* colsum  = (unsigned long long*)(w + (size_t)HWN * 12); // 16 MB
    uint8_t* flags              = (uint8_t*)(w + (size_t)HWN * 20);   //  2 MB
    signed char* chan           = (signed char*)(w + (size_t)HWN * 21); // 2 MB
    int* cand                   = (int*)(w + (size_t)HWN * 22);       // 280 KB
    int* counter                = (int*)(w + (size_t)HWN * 22 + MAXCAND * 4);  // [0]=n,[1]=done
    unsigned long long* top26g  = (unsigned long long*)(w + (size_t)HWN * 22 + MAXCAND * 4 + 256);

    // no memsets: k_local zeros sizes/colsum/chan/counter/done
    const int blocks = HWN / THREADS;   // 8192
    k_local       <<<NTILES, LTHREADS, 0, stream>>>(mask, flags, parent,
                                                    sizes, colsum, chan, counter);
    k_merge       <<<NTILES, THREADS, 0, stream>>>(flags, parent);
    k_border_stats<<<blocks, THREADS, 0, stream>>>(flags, parent, labfull, sizes, colsum,
                                                   cand, counter);
    k_sel         <<<NB, THREADS, 0, stream>>>(cand, counter, sizes, colsum, top26g, chan);
    k_output      <<<HWN / (4 * THREADS), THREADS, 0, stream>>>(labfull, chan, out);
}

// Round 11
// 388.101 us; speedup vs baseline: 3.0544x; 1.0445x over previous
//
#include <hip/hip_runtime.h>
#include <stdint.h>

#define HH 1024
#define WW 2048
#define HWN (HH*WW)          // 2097152
#define BIGL HWN             // 'no cluster' sentinel
#define NSLOTS 26
#define MINCL 30
#define THREADS 256
#define LTHREADS 512         // k_local block size (8 waves)
#define MAXCAND 70000        // >= HWN/30 + 1
#define HSZ 512              // per-block LDS hash entries
#define TILE 4096            // 64x64 tile
#define NTILES 512           // (1024/64)*(2048/64)
#define NB 128               // selection blocks

typedef int vi4 __attribute__((ext_vector_type(4)));
typedef unsigned long long u64;

// ---------------- global union-find (lock-free, min-root) ----------------
__device__ __forceinline__ int uf_load(int* p, int i) {
    return __hip_atomic_load(&p[i], __ATOMIC_RELAXED, __HIP_MEMORY_SCOPE_AGENT);
}
__device__ __forceinline__ void uf_store(int* p, int i, int v) {
    __hip_atomic_store(&p[i], v, __ATOMIC_RELAXED, __HIP_MEMORY_SCOPE_AGENT);
}
__device__ int uf_find(int* parent, int x) {
    int p = uf_load(parent, x);
    while (p != x) {
        int gp = uf_load(parent, p);
        if (gp != p) uf_store(parent, x, gp);   // path halving (benign race)
        x = p; p = gp;
    }
    return p;
}
__device__ void uf_union(int* parent, int a, int b) {
    int ra = uf_find(parent, a);
    int rb = uf_find(parent, b);
    while (ra != rb) {
        if (ra > rb) { int t = ra; ra = rb; rb = t; }   // hook larger under smaller
        int old = atomicCAS(&parent[rb], rb, ra);
        if (old == rb) return;
        rb = uf_find(parent, old);
        ra = uf_find(parent, ra);
    }
}

// ---------------- LDS union-find (block-local, min-root) ----------------
__device__ __forceinline__ int l_load(int* p, int i) {
    return __hip_atomic_load(&p[i], __ATOMIC_RELAXED, __HIP_MEMORY_SCOPE_WORKGROUP);
}
__device__ __forceinline__ void l_store(int* p, int i, int v) {
    __hip_atomic_store(&p[i], v, __ATOMIC_RELAXED, __HIP_MEMORY_SCOPE_WORKGROUP);
}
__device__ int l_find(int* lp, int x) {
    int p = l_load(lp, x);
    while (p != x) {
        int gp = l_load(lp, p);
        if (gp != p) l_store(lp, x, gp);
        x = p; p = gp;
    }
    return p;
}
__device__ void l_union(int* lp, int a, int b) {
    int ra = l_find(lp, a);
    int rb = l_find(lp, b);
    while (ra != rb) {
        if (ra > rb) { int t = ra; ra = rb; rb = t; }
        int old = atomicCAS(&lp[rb], rb, ra);
        if (old == rb) return;
        rb = l_find(lp, old);
        ra = l_find(lp, ra);
    }
}

// ---------------- fused init + per-tile CC + ws zeroing ----------------
__global__ __launch_bounds__(LTHREADS) void k_local(const float* __restrict__ mask,
                                                    uint8_t* __restrict__ flags,
                                                    int* __restrict__ parent,
                                                    int* __restrict__ sizes,
                                                    unsigned long long* __restrict__ colsum,
                                                    signed char* __restrict__ chan,
                                                    int* __restrict__ counter) {
    __shared__ uint8_t lact[66 * 72];   // halo active map, row stride 72
    __shared__ uint8_t lc8[TILE];
    __shared__ int lp[TILE];
    const int tid = threadIdx.x;
    int tile_x = blockIdx.x & 31, tile_y = blockIdx.x >> 5;
    int r0 = tile_y << 6, c0 = tile_x << 6;

    {   // zero this block's 1/512 slice of sizes/colsum/chan (+counter/done once)
        int base = blockIdx.x * (HWN / NTILES);      // 4096 elements
        vi4* sz4 = (vi4*)(sizes + base);
        vi4* cs4 = (vi4*)(colsum + base);
        for (int t = tid; t < 1024; t += LTHREADS) sz4[t] = (vi4)0;
        for (int t = tid; t < 2048; t += LTHREADS) cs4[t] = (vi4)0;
        vi4* ch4 = (vi4*)(chan + base);
        for (int t = tid; t < 256; t += LTHREADS) ch4[t] = (vi4)(-1);
        if (blockIdx.x == 0 && tid == 0) { counter[0] = 0; counter[1] = 0; }
    }

    {   // body rows: 64 rows x 16 float4, coalesced; 512 threads -> 2 passes
        int lr = tid >> 4, q = tid & 15;
        #pragma unroll
        for (int pass = 0; pass < 2; ++pass) {
            int rr = lr + pass * 32;
            const float4* src = (const float4*)(mask + (size_t)(r0 + rr) * WW + c0);
            float4 v = src[q];
            uint8_t* dst = &lact[(rr + 1) * 72 + (q * 4 + 1)];
            dst[0] = v.x > 0.1f; dst[1] = v.y > 0.1f;
            dst[2] = v.z > 0.1f; dst[3] = v.w > 0.1f;
        }
    }
    if (tid < 32) {          // halo top/bottom rows (cols 1..64)
        int q = tid & 15;
        bool top = tid < 16;
        int gr = top ? r0 - 1 : r0 + 64;
        int yy = top ? 0 : 65;
        uint8_t* dst = &lact[yy * 72 + (q * 4 + 1)];
        if ((unsigned)gr < HH) {
            const float4* src = (const float4*)(mask + (size_t)gr * WW + c0);
            float4 v = src[q];
            dst[0] = v.x > 0.1f; dst[1] = v.y > 0.1f;
            dst[2] = v.z > 0.1f; dst[3] = v.w > 0.1f;
        } else {
            dst[0] = 0; dst[1] = 0; dst[2] = 0; dst[3] = 0;
        }
    } else if (tid >= 64 && tid < 64 + 132) {   // halo cols incl corners
        int lane = tid - 64;                    // 0..131
        int side = lane >= 66;                  // 0=left(c0-1), 1=right(c0+64)
        int yy = side ? lane - 66 : lane;       // 0..65
        int gr = r0 - 1 + yy;
        int gc = side ? c0 + 64 : c0 - 1;
        bool a = false;
        if ((unsigned)gr < HH && (unsigned)gc < WW) a = mask[(size_t)gr * WW + gc] > 0.1f;
        lact[yy * 72 + (side ? 65 : 0)] = a ? 1 : 0;
    }
    __syncthreads();
    for (int li = tid; li < TILE; li += LTHREADS) {
        int lr = li >> 6, lc = li & 63;
        int b = (lr + 1) * 72 + (lc + 1);
        int a = lact[b];
        int cnt = lact[b - 73] + lact[b - 72] + lact[b - 71]
                + lact[b - 1]  + a           + lact[b + 1]
                + lact[b + 71] + lact[b + 72] + lact[b + 73];
        lc8[li] = (uint8_t)(a | ((a && cnt >= 4) ? 2 : 0));  // MIN_SAMPLES=4 incl self
        lp[li] = li;
    }
    __syncthreads();
    if (tid < 256) {   // flags -> global, 16B per thread
        int row = tid >> 2, chunk = tid & 3;
        ((uint4*)(flags + (size_t)(r0 + row) * WW + c0))[chunk] =
            ((const uint4*)lc8)[row * 4 + chunk];
    }
    for (int li = tid; li < TILE; li += LTHREADS) {
        if (!(lc8[li] & 2)) continue;
        int lr = li >> 6, lc = li & 63;
        if (lc > 0 && (lc8[li - 1] & 2)) l_union(lp, li, li - 1);
        if (lr > 0) {
            if (lc > 0  && (lc8[li - 65] & 2)) l_union(lp, li, li - 65);
            if (           (lc8[li - 64] & 2)) l_union(lp, li, li - 64);
            if (lc < 63 && (lc8[li - 63] & 2)) l_union(lp, li, li - 63);
        }
    }
    __syncthreads();
    for (int li = tid; li < TILE; li += LTHREADS) {
        if (!(lc8[li] & 2)) continue;
        int root = li, p;
        while ((p = lp[root]) != root) root = p;   // lp stable after barrier
        int gi = (r0 + (li >> 6)) * WW + c0 + (li & 63);
        int gr = (r0 + (root >> 6)) * WW + c0 + (root & 63);
        parent[gi] = gr;
    }
}

// union only tile-crossing edges (R10-identical)
__global__ __launch_bounds__(THREADS) void k_merge(const uint8_t* __restrict__ flags,
                                                   int* __restrict__ parent) {
    int tile_x = blockIdx.x & 31, tile_y = blockIdx.x >> 5;
    int r0 = tile_y << 6, c0 = tile_x << 6;
    int t = threadIdx.x;
    int lane = t & 63;

    if (t < 64) {                                    // top row, lr=0, lc=t
        int r = r0, c = c0 + t, i = r * WW + c;
        bool selfC = (flags[i] & 2) != 0;
        bool nC = false, nwC = false, neC = false;
        if (selfC && r > 0) {
            nC  = (flags[i - WW] & 2) != 0;
            nwC = (c > 0)      && (flags[i - WW - 1] & 2);
            neC = (c < WW - 1) && (flags[i - WW + 1] & 2);
        }
        int did = 0, ra = -1, rb = -1;
        if (selfC && r > 0 && nC) { ra = uf_find(parent, i); rb = uf_find(parent, i - WW); did = 1; }
        int pra = __shfl_up(ra, 1), prb = __shfl_up(rb, 1), pdid = __shfl_up(did, 1);
        bool head = (lane == 0) || !pdid || pra != ra || prb != rb;
        if (did && head) uf_union(parent, ra, rb);
        if (selfC && r > 0) {
            if (t == 0) {
                if (nwC) uf_union(parent, i, i - WW - 1);          // diag tile
                if (!nC && neC) uf_union(parent, i, i - WW + 1);
            } else if (t == 63) {
                if (!nC && nwC) uf_union(parent, i, i - WW - 1);
                if (neC) {
                    bool eC = (c < WW - 1) && (flags[i + 1] & 2);
                    if (!eC) uf_union(parent, i, i - WW + 1);
                }
            } else if (!nC) {
                if (nwC) uf_union(parent, i, i - WW - 1);
                if (neC) uf_union(parent, i, i - WW + 1);
            }
        }
        if (t == 0 && selfC && c > 0 && (flags[i - 1] & 2))        // corner W edge
            uf_union(parent, i, i - 1);
    } else if (t < 127) {                            // left col, lr=1..63, lc=0
        int lr = t - 63;
        int r = r0 + lr, c = c0, i = r * WW + c;
        bool selfC = (flags[i] & 2) != 0;
        bool wC = false, nwC = false;
        if (selfC && c > 0) {
            wC  = (flags[i - 1] & 2) != 0;
            nwC = (flags[i - WW - 1] & 2) != 0;
        }
        int did = 0, ra = -1, rb = -1;
        if (selfC && wC) { ra = uf_find(parent, i); rb = uf_find(parent, i - 1); did = 1; }
        int pra = __shfl_up(ra, 1), prb = __shfl_up(rb, 1), pdid = __shfl_up(did, 1);
        bool head = (lane == 0) || !pdid || pra != ra || prb != rb;
        if (did && head) uf_union(parent, ra, rb);
        if (selfC && !wC && nwC) uf_union(parent, i, i - WW - 1);
    } else if (t < 190) {                            // right col, lr=1..63, lc=63
        int lr = t - 126;
        int r = r0 + lr, c = c0 + 63, i = r * WW + c;
        bool selfC = (flags[i] & 2) != 0;
        if (selfC && c < WW - 1) {
            bool neC = (flags[i - WW + 1] & 2) != 0;
            bool eC  = (flags[i + 1] & 2) != 0;
            if (neC && !eC) uf_union(parent, i, i - WW + 1);
        }
    }
}

// ---------------- border + stats with parent-value dedupe ----------------
// Core pixels' parent[i] is (near-)star: a strip touches few distinct parent
// values. Dedupe via LDS hash -> ONE uf_find per distinct value per block.
__device__ __forceinline__ void h_insert(int* h_key, int p) {
    unsigned slot = (((unsigned)p * 2654435761u) >> 20) & (HSZ - 1);
    for (;;) {
        int old = atomicCAS(&h_key[slot], -1, p);
        if (old == -1 || old == p) return;
        slot = (slot + 1) & (HSZ - 1);
    }
}
__device__ __forceinline__ int h_lookup(const int* h_key, const int* h_root, int p) {
    unsigned slot = (((unsigned)p * 2654435761u) >> 20) & (HSZ - 1);
    for (;;) {
        if (h_key[slot] == p) return h_root[slot];
        slot = (slot + 1) & (HSZ - 1);
    }
}

__global__ __launch_bounds__(THREADS) void k_border_stats(
        const uint8_t* __restrict__ flags, int* __restrict__ parent,
        int* __restrict__ labfull, int* __restrict__ sizes,
        unsigned long long* __restrict__ colsum,
        int* __restrict__ cand, int* __restrict__ counter) {
    __shared__ int h_key[HSZ];
    __shared__ int h_root[HSZ];
    __shared__ int s_lab[HSZ];
    __shared__ int s_sz[HSZ];
    __shared__ u64 s_cs[HSZ];
    for (int t = threadIdx.x; t < HSZ; t += THREADS) {
        h_key[t] = -1; s_lab[t] = -1; s_sz[t] = 0; s_cs[t] = 0;
    }
    __syncthreads();

    const int i = blockIdx.x * THREADS + threadIdx.x;
    const int f = flags[i];
    const int r = i >> 11, c = i & (WW - 1);

    int pself = -1;
    int pnb[8];
    #pragma unroll
    for (int t = 0; t < 8; ++t) pnb[t] = -1;

    if (f & 2) {
        pself = parent[i];                       // coalesced
        h_insert(h_key, pself);
    } else if (f & 1) {                          // active non-core
        const int dr8[8] = {-1,-1,-1, 0,0, 1,1,1};
        const int dc8[8] = {-1, 0, 1,-1,1,-1,0,1};
        #pragma unroll
        for (int t = 0; t < 8; ++t) {
            int rr = r + dr8[t], cc = c + dc8[t];
            if ((unsigned)rr < HH && (unsigned)cc < WW) {
                int n = rr * WW + cc;
                if (flags[n] & 2) {
                    int p = parent[n];
                    pnb[t] = p;
                    h_insert(h_key, p);
                }
            }
        }
    }
    __syncthreads();
    // resolve each distinct parent value once
    for (int t = threadIdx.x; t < HSZ; t += THREADS) {
        int k = h_key[t];
        if (k >= 0) h_root[t] = uf_find(parent, k);
    }
    __syncthreads();

    int lab = BIGL;
    if (f & 2) {
        lab = h_lookup(h_key, h_root, pself);
    } else if (f & 1) {
        int m = BIGL;
        #pragma unroll
        for (int t = 0; t < 8; ++t)
            if (pnb[t] >= 0) { int v = h_lookup(h_key, h_root, pnb[t]); if (v < m) m = v; }
        lab = m;                     // BIGL if no core neighbor
    }
    labfull[i] = lab;

    // wave-level run aggregation (WW % 64 == 0: wave never crosses a row)
    int lane = threadIdx.x & 63;
    int labp = __shfl_up(lab, 1);
    bool head = (lane == 0) || (labp != lab);
    unsigned long long hm = __ballot(head);
    if (head && lab < BIGL) {
        unsigned long long rest = (hm >> lane) >> 1;
        int len = rest ? __ffsll((unsigned long long)rest) : (64 - lane);
        long long cc0 = (long long)(i & (WW - 1));
        u64 csum = (u64)(cc0 * len + (long long)len * (len - 1) / 2);
        unsigned slot = (((unsigned)lab * 2654435761u) >> 20) & (HSZ - 1);
        for (;;) {
            int old = atomicCAS(&s_lab[slot], -1, lab);
            if (old == -1 || old == lab) {
                atomicAdd(&s_sz[slot], len);
                atomicAdd(&s_cs[slot], csum);
                break;
            }
            slot = (slot + 1) & (HSZ - 1);
        }
    }
    __syncthreads();
    for (int t = threadIdx.x; t < HSZ; t += THREADS) {
        int lb = s_lab[t];
        if (lb >= 0) {
            int add = s_sz[t];
            int old = atomicAdd(&sizes[lb], add);
            if (old < MINCL && old + add >= MINCL) {   // exactly one block sees this
                int p = atomicAdd(counter, 1);
                cand[p] = lb;
            }
            atomicAdd(&colsum[lb], s_cs[t]);
        }
    }
}

// ---- fused single-kernel top-26 selection (R10-identical) ----
__device__ __forceinline__ u64 wave_min_u64(u64 m) {
    #pragma unroll
    for (int off = 32; off; off >>= 1) {
        u64 o = __shfl_xor(m, off);
        if (o < m) m = o;
    }
    return m;
}

__global__ __launch_bounds__(THREADS) void k_sel(const int* __restrict__ cand,
                                                 int* __restrict__ counter,   // [0]=n, [1]=done
                                                 const int* __restrict__ sizes,
                                                 const unsigned long long* __restrict__ colsum,
                                                 unsigned long long* __restrict__ top26g,
                                                 signed char* __restrict__ chan) {
    __shared__ u64 wout[4 * NSLOTS];
    const int tid = threadIdx.x, lane = tid & 63, wv = tid >> 6;
    const int n = counter[0];
    int slice = (n + NB - 1) / NB;
    int j0 = blockIdx.x * slice;
    int j1 = j0 + slice; if (j1 > n) j1 = n;
    int len = j1 - j0; if (len < 0) len = 0;
    int chunk = (len + 3) >> 2;
    int s0 = j0 + wv * chunk;
    int s1 = s0 + chunk; if (s1 > j1) s1 = j1;

    u64 kk[3] = { ~0ull, ~0ull, ~0ull };
    #pragma unroll
    for (int t = 0; t < 3; ++t) {
        int j = s0 + lane + 64 * t;
        if (j < s1) {
            int lab = cand[j];
            float mean = (float)colsum[lab] / (float)sizes[lab];
            kk[t] = ((u64)__float_as_uint(mean) << 32) | (unsigned)lab;
        }
    }
    for (int k = 0; k < NSLOTS; ++k) {
        u64 m = kk[0]; int li = 0;
        if (kk[1] < m) { m = kk[1]; li = 1; }
        if (kk[2] < m) { m = kk[2]; li = 2; }
        u64 mpre = m;
        m = wave_min_u64(m);
        if (mpre == m && m != ~0ull) kk[li] = ~0ull;
        if (lane == 0) wout[wv * NSLOTS + k] = m;
    }
    __syncthreads();
    if (wv == 0) {
        u64 a = (lane < 4 * NSLOTS) ? wout[lane] : ~0ull;
        u64 b = (lane + 64 < 4 * NSLOTS) ? wout[lane + 64] : ~0ull;
        for (int k = 0; k < NSLOTS; ++k) {
            u64 m = a < b ? a : b; int li = a < b ? 0 : 1;
            u64 mpre = m;
            m = wave_min_u64(m);
            if (mpre == m && m != ~0ull) { if (li == 0) a = ~0ull; else b = ~0ull; }
            if (lane == 0) top26g[blockIdx.x * NSLOTS + k] = m;
        }
    }
    __syncthreads();
    __shared__ int lastflag;
    if (tid == 0) {
        __threadfence();
        lastflag = (atomicAdd(&counter[1], 1) == NB - 1);
    }
    __syncthreads();
    if (!lastflag) return;

    u64 mk[13];
    #pragma unroll
    for (int t = 0; t < 13; ++t) {
        int j = wv * 832 + lane + 64 * t;
        mk[t] = __hip_atomic_load(&top26g[j], __ATOMIC_RELAXED, __HIP_MEMORY_SCOPE_AGENT);
    }
    for (int k = 0; k < NSLOTS; ++k) {
        u64 m = mk[0]; int li = 0;
        #pragma unroll
        for (int t = 1; t < 13; ++t) if (mk[t] < m) { m = mk[t]; li = t; }
        u64 mpre = m;
        m = wave_min_u64(m);
        if (mpre == m && m != ~0ull) mk[li] = ~0ull;
        if (lane == 0) wout[wv * NSLOTS + k] = m;
    }
    __syncthreads();
    if (wv == 0) {
        u64 a = (lane < 4 * NSLOTS) ? wout[lane] : ~0ull;
        u64 b = (lane + 64 < 4 * NSLOTS) ? wout[lane + 64] : ~0ull;
        for (int k = 0; k < NSLOTS; ++k) {
            u64 m = a < b ? a : b; int li = a < b ? 0 : 1;
            u64 mpre = m;
            m = wave_min_u64(m);
            if (mpre == m && m != ~0ull) { if (li == 0) a = ~0ull; else b = ~0ull; }
            if (lane == 0 && m != ~0ull)
                chan[(unsigned int)(m & 0xFFFFFFFFull)] = (signed char)k;
        }
    }
}

// one-hot 26xHxW int32 output, non-temporal int4 stores (R10-identical)
__global__ __launch_bounds__(THREADS) void k_output(const int* __restrict__ labfull,
                                                    const signed char* __restrict__ chan,
                                                    int* __restrict__ out) {
    int i4 = (blockIdx.x * THREADS + threadIdx.x) * 4;
    int chv[4];
    #pragma unroll
    for (int t = 0; t < 4; ++t) {
        int lab = labfull[i4 + t];
        chv[t] = (lab < BIGL) ? (int)chan[lab] : -1;
    }
    #pragma unroll
    for (int c = 0; c < NSLOTS; ++c) {
        vi4 v;
        v.x = (chv[0] == c) ? 1 : 0;
        v.y = (chv[1] == c) ? 1 : 0;
        v.z = (chv[2] == c) ? 1 : 0;
        v.w = (chv[3] == c) ? 1 : 0;
        __builtin_nontemporal_store(v, (vi4*)(out + (size_t)c * HWN + i4));
    }
}

extern "C" void kernel_launch(void* const* d_in, const int* in_sizes, int n_in,
                              void* d_out, int out_size, void* d_ws, size_t ws_size,
                              hipStream_t stream) {
    const float* mask = (const float*)d_in[0];
    int* out = (int*)d_out;

    char* w = (char*)d_ws;
    int* parent                 = (int*)(w);                          //  8 MB
    int* labfull                = (int*)(w + (size_t)HWN * 4);        //  8 MB
    int* sizes                  = (int*)(w + (size_t)HWN * 8);        //  8 MB
    unsigned long long* colsum  = (unsigned long long*)(w + (size_t)HWN * 12); // 16 MB
    uint8_t* flags              = (uint8_t*)(w + (size_t)HWN * 20);   //  2 MB
    signed char* chan           = (signed char*)(w + (size_t)HWN * 21); // 2 MB
    int* cand                   = (int*)(w + (size_t)HWN * 22);       // 280 KB
    int* counter                = (int*)(w + (size_t)HWN * 22 + MAXCAND * 4);  // [0]=n,[1]=done
    unsigned long long* top26g  = (unsigned long long*)(w + (size_t)HWN * 22 + MAXCAND * 4 + 256);

    // no memsets: k_local zeros sizes/colsum/chan/counter/done
    const int blocks = HWN / THREADS;   // 8192
    k_local       <<<NTILES, LTHREADS, 0, stream>>>(mask, flags, parent,
                                                    sizes, colsum, chan, counter);
    k_merge       <<<NTILES, THREADS, 0, stream>>>(flags, parent);
    k_border_stats<<<blocks, THREADS, 0, stream>>>(flags, parent, labfull, sizes, colsum,
                                                   cand, counter);
    k_sel         <<<NB, THREADS, 0, stream>>>(cand, counter, sizes, colsum, top26g, chan);
    k_output      <<<HWN / (4 * THREADS), THREADS, 0, stream>>>(labfull, chan, out);
}